// Round 8
// baseline (156.395 us; speedup 1.0000x reference)
//
#include <hip/hip_runtime.h>
#include <math.h>

// Problem constants (MultiQueryAttention_20229295964202)
#define BATCH   4
#define SEQQ    2048
#define SEQK    2048
#define DMODEL  512
#define NHEADS  8
#define PDIM    64

#define QSCALE  0.18033688f   // 0.125 * log2(e); folded into Wq/bq; exp2 softmax

typedef __attribute__((ext_vector_type(8))) short short8;   // 8 bf16 (4 VGPRs)
typedef __attribute__((ext_vector_type(4))) float f32x4;    // MFMA C/D frag

__device__ __forceinline__ unsigned short f2bf(float x) {   // RNE
    unsigned u = __builtin_bit_cast(unsigned, x);
    u += 0x7fffu + ((u >> 16) & 1u);
    return (unsigned short)(u >> 16);
}
__device__ __forceinline__ unsigned pack_bf16_rh(float lo, float hi) {
    unsigned ul = __builtin_bit_cast(unsigned, lo) + 0x8000u;
    unsigned uh = __builtin_bit_cast(unsigned, hi) + 0x8000u;
    return __builtin_amdgcn_perm(uh, ul, 0x07060302u);  // [uh.hi16 : ul.hi16]
}
__device__ __forceinline__ float exp2_raw(float x) {        // raw v_exp_f32
    return __builtin_amdgcn_exp2f(x);
}
// async global->LDS, 16B/lane; lds base is wave-uniform, HW adds lane*16
__device__ __forceinline__ void glds16(const void* g, void* l) {
    __builtin_amdgcn_global_load_lds(
        (const __attribute__((address_space(1))) void*)g,
        (__attribute__((address_space(3))) void*)l, 16, 0, 0);
}

// ---------------------------------------------------------------------------
// Weight transpose: Wt[mat][n][k] bf16 (mat 0-7=Wq*QSCALE, 8=Wk, 9=Wv, 10=Wo).
// grid 88 = (mat, k-chunk): no serial loop.
// ---------------------------------------------------------------------------
__global__ __launch_bounds__(256) void convert_w_kernel(
    const float* __restrict__ Wq, const float* __restrict__ Wk,
    const float* __restrict__ Wv, const float* __restrict__ Wo,
    unsigned short* __restrict__ Wt)
{
    const int tid = threadIdx.x;
    const int mat = blockIdx.x >> 3;           // 0..10
    const int k0 = (blockIdx.x & 7) << 6;      // 0..448
    const float sc = (mat < 8) ? QSCALE : 1.0f;
    const float* src = (mat < 8) ? (Wq + (size_t)mat * 32768)
                     : (mat == 8) ? Wk : (mat == 9) ? Wv : Wo;
    __shared__ unsigned short T[64][72];       // [n][k-sub], padded
#pragma unroll
    for (int it = 0; it < 4; ++it) {
        int flat = tid * 4 + 1024 * it;        // k*64 + n
        int k = flat >> 6, n = flat & 63;
        float4 v = *(const float4*)(src + (size_t)(k0 + k) * 64 + n);
        T[n + 0][k] = f2bf(v.x * sc);
        T[n + 1][k] = f2bf(v.y * sc);
        T[n + 2][k] = f2bf(v.z * sc);
        T[n + 3][k] = f2bf(v.w * sc);
    }
    __syncthreads();
    int n = tid >> 2, kk = (tid & 3) * 16;
    uint4 w0 = *(const uint4*)(&T[n][kk]);
    uint4 w1 = *(const uint4*)(&T[n][kk + 8]);
    *(uint4*)(Wt + (size_t)mat * 32768 + (size_t)n * 512 + k0 + kk) = w0;
    *(uint4*)(Wt + (size_t)mat * 32768 + (size_t)n * 512 + k0 + kk + 8) = w1;
}

// ---------------------------------------------------------------------------
// QKV projection, fp32 X read directly (cvt in staging). 32-row x 256-col
// tiles; grid (256, 3): slot 0 = heads 0-3, slot 1 = heads 4-7, slot 2 = K|V.
// X float4 loads for the next chunk are issued AFTER the second barrier so
// their L3 latency hides under the MFMAs.
// ---------------------------------------------------------------------------
__global__ __launch_bounds__(256, 4) void qkv_proj_kernel(
    const float* __restrict__ query, const float* __restrict__ store_,
    const unsigned short* __restrict__ Wt,
    const float* __restrict__ bq, const float* __restrict__ bk,
    const float* __restrict__ bv,
    unsigned short* __restrict__ Qbuf, unsigned short* __restrict__ Kbuf,
    unsigned short* __restrict__ Vtbuf)
{
    __shared__ unsigned short Xt[2560];         // X tile [32][72] / Vlds [64][40]
    __shared__ unsigned short Wtile[256 * 64];  // 32768 B, XOR swizzle

    const int slot = blockIdx.y;
    const int row0 = blockIdx.x * 32;
    const int b = row0 >> 11;
    const int s0 = row0 & 2047;

    const float* X = ((slot < 2) ? query : store_) + (size_t)row0 * 512;
    const unsigned short* Wbase = Wt + (size_t)(slot * 4) * 32768;  // slot2 -> mats 8,9

    const int tid = threadIdx.x;
    const int wv = tid >> 6, lane = tid & 63;
    const int g = lane >> 4, c16 = lane & 15;
    const int c8 = c16 & 7;
    const int sm = wv & 1;
    const int uh = wv >> 1;
    const int lrow = lane >> 3;
    const int lcol = ((lane & 7) ^ lrow) * 8;   // swizzled col (shorts)

    f32x4 z = {0.f, 0.f, 0.f, 0.f};
    f32x4 acc[8] = {z, z, z, z, z, z, z, z};

    const int xrow = tid >> 3;                  // 0..31
    const int xcol = (tid & 7) * 8;             // 0..56
    const int nwr = (slot < 2) ? 8 : 4;         // W row-blocks per wave

    float4 xa = *(const float4*)(X + (size_t)xrow * 512 + xcol);
    float4 xb = *(const float4*)(X + (size_t)xrow * 512 + xcol + 4);

    for (int k0 = 0; k0 < 512; k0 += 64) {
        __syncthreads();   // prev chunk's MFMA reads of Xt/Wtile done
        for (int j = 0; j < nwr; ++j) {
            int rb = (nwr * wv + j) * 8;
            glds16(Wbase + (size_t)(rb + lrow) * 512 + k0 + lcol, Wtile + rb * 64);
        }
        ushort4 o0, o1;
        o0.x = f2bf(xa.x); o0.y = f2bf(xa.y); o0.z = f2bf(xa.z); o0.w = f2bf(xa.w);
        o1.x = f2bf(xb.x); o1.y = f2bf(xb.y); o1.z = f2bf(xb.z); o1.w = f2bf(xb.w);
        *(ushort4*)(&Xt[xrow * 72 + xcol]) = o0;
        *(ushort4*)(&Xt[xrow * 72 + xcol + 4]) = o1;
        __syncthreads();   // drains glds + lds stores

        if (k0 < 448) {    // prefetch next X chunk; lands under the MFMAs
            xa = *(const float4*)(X + (size_t)xrow * 512 + k0 + 64 + xcol);
            xb = *(const float4*)(X + (size_t)xrow * 512 + k0 + 64 + xcol + 4);
        }

        if (slot < 2) {
#pragma unroll
            for (int ks = 0; ks < 2; ++ks) {
                short8 aX = *(const short8*)(&Xt[(16 * sm + c16) * 72 + 32 * ks + 8 * g]);
#pragma unroll
                for (int uu = 0; uu < 8; ++uu) {
                    int u = 8 * uh + uu;
                    short8 bW = *(const short8*)(Wtile + (16 * u + c16) * 64 + ((4 * ks + g) ^ c8) * 8);
                    acc[uu] = __builtin_amdgcn_mfma_f32_16x16x32_bf16(aX, bW, acc[uu], 0, 0, 0);
                }
            }
        } else {
#pragma unroll
            for (int ks = 0; ks < 2; ++ks) {
                short8 aX = *(const short8*)(&Xt[(16 * sm + c16) * 72 + 32 * ks + 8 * g]);
#pragma unroll
                for (int uu = 0; uu < 4; ++uu) {
                    int u = 4 * uh + uu;
                    short8 bW = *(const short8*)(Wtile + (16 * u + c16) * 64 + ((4 * ks + g) ^ c8) * 8);
                    acc[uu] = __builtin_amdgcn_mfma_f32_16x16x32_bf16(aX, bW, acc[uu], 0, 0, 0);
                }
            }
        }
    }

    if (slot < 2) {
        // 4 Q heads; wave uh covers heads 2uh, 2uh+1 of this slot
#pragma unroll
        for (int uu = 0; uu < 8; ++uu) {
            int u = 8 * uh + uu;
            int head = 4 * slot + (u >> 2);
            int pc = 16 * (u & 3) + c16;
            float bb = QSCALE * bq[head * 64 + pc];
            unsigned short* Y = Qbuf + ((size_t)(b * NHEADS + head) * SEQQ + s0) * PDIM;
#pragma unroll
            for (int r = 0; r < 4; ++r)
                Y[(size_t)(16 * sm + 4 * g + r) * PDIM + pc] = f2bf(acc[uu][r] + bb);
        }
    } else {
        // uh==0 waves hold K (u 0..3); uh==1 waves hold V (u 4..7)
        if (uh == 0) {
            unsigned short* Yk = Kbuf + (size_t)row0 * PDIM;
#pragma unroll
            for (int uu = 0; uu < 4; ++uu) {
                float bb = bk[16 * uu + c16];
#pragma unroll
                for (int r = 0; r < 4; ++r)
                    Yk[(size_t)(16 * sm + 4 * g + r) * PDIM + 16 * uu + c16] =
                        f2bf(acc[uu][r] + bb);
            }
        }
        __syncthreads();   // Xt MFMA reads done; reuse as Vlds[64][40]
        if (uh == 1) {
#pragma unroll
            for (int uu = 0; uu < 4; ++uu) {
                int p = 16 * uu + c16;
                float bb = bv[p];
#pragma unroll
                for (int r = 0; r < 4; ++r)
                    Xt[p * 40 + 16 * sm + 4 * g + r] = f2bf(acc[uu][r] + bb);
            }
        }
        __syncthreads();
        int p = tid >> 2, soff = (tid & 3) * 8;
        uint4 w = *(const uint4*)(&Xt[p * 40 + soff]);
        *(uint4*)(Vtbuf + (size_t)b * PDIM * SEQK + (size_t)p * SEQK + s0 + soff) = w;
    }
}

// ---------------------------------------------------------------------------
// Flash attention R17: NO K-SPLIT at preserved residency. 128 q/block,
// 4 waves (32 q/wave, y=0..1), grid (16,8,4) = 512 blocks = 2/CU (R15's
// regression was 256-q blocks -> 1/CU; this keeps R14's residency).
// Proven R14 dbuf datapath, 32 KV-iters. Epilogue normalizes in-register
// (iv = 1/lacc) and writes a SINGLE rawO (8.4MB) -> out_proj combine pass
// and Lraw are gone.
// LDS: K dbuf 16K | V dbuf 16K | Ps 8K = 40KB -> 2 blocks/CU.
// ---------------------------------------------------------------------------
__global__ __launch_bounds__(256, 2) void attn_kernel(
    const unsigned short* __restrict__ Qbuf,
    const unsigned short* __restrict__ Kbuf,
    const unsigned short* __restrict__ Vtbuf,
    unsigned int* __restrict__ rawO)    // [rawblk 512][slot 32][lane 64] uint2
{
    __shared__ unsigned short smem[20480];  // K dbuf 8192 | V dbuf 8192 | Ps 4096
    unsigned short* Kb = smem;
    unsigned short* Vb = smem + 8192;
    unsigned short* Ps = smem + 16384;

    const int tid = threadIdx.x;
    const int wv = tid >> 6;
    const int lane = tid & 63;
    const int g = lane >> 4;
    const int c16 = lane & 15;
    const int c8 = c16 & 7;
    const int b = blockIdx.z;
    const int h = blockIdx.y;
    const int qt = blockIdx.x;
    const int q0 = qt * 128;

    const int lrow = lane >> 3;
    const int lcol = ((lane & 7) ^ lrow) * 8;

    // stage 128 q rows (16 KB) into the K/V dbuf region
    const unsigned short* Qp = Qbuf + ((size_t)(b * NHEADS + h) * SEQQ + q0) * PDIM;
#pragma unroll
    for (int j = 0; j < 4; ++j) {
        int rowblk = (4 * wv + j) * 8;
        glds16(Qp + (size_t)(rowblk + lrow) * PDIM + lcol, smem + rowblk * 64);
    }
    __syncthreads();

    short8 bQ[2][2];   // B[k=p][n=query=c16], wave rows 32*wv + 16*y
#pragma unroll
    for (int y = 0; y < 2; ++y)
#pragma unroll
        for (int ks = 0; ks < 2; ++ks)
            bQ[y][ks] = *(const short8*)(smem + (32 * wv + 16 * y + c16) * 64 +
                                         ((4 * ks + g) ^ c8) * 8);
    __syncthreads();

    const unsigned short* Kp  = Kbuf  + (size_t)b * SEQK * PDIM;
    const unsigned short* Vtp = Vtbuf + (size_t)b * PDIM * SEQK;

#pragma unroll
    for (int j = 0; j < 2; ++j) {
        int rb = (2 * wv + j) * 8;
        glds16(Kp + (size_t)(rb + lrow) * PDIM + lcol, Kb + rb * 64);
        glds16(Vtp + (size_t)(rb + lrow) * SEQK + lcol, Vb + rb * 64);
    }

    const short one_bf = (short)0x3F80;   // bf16 1.0
    short8 vones = {one_bf, one_bf, one_bf, one_bf, one_bf, one_bf, one_bf, one_bf};

    f32x4 z = {0.f, 0.f, 0.f, 0.f};
    f32x4 oacc[2][4] = {{z, z, z, z}, {z, z, z, z}};
    f32x4 lacc[2] = {z, z};
    unsigned short* PsW = Ps + wv * 1024;   // 16 x 64, reused per y (in-order LDS)

    for (int i = 0; i < 32; ++i) {
        __syncthreads();   // drains glds(tile i); prev compute reads done
        const unsigned short* Kc = Kb + (i & 1) * 4096;
        const unsigned short* Vc = Vb + (i & 1) * 4096;
        if (i < 31) {
            int t0 = (i + 1) * 64;
            unsigned short* Kn = Kb + ((i + 1) & 1) * 4096;
            unsigned short* Vn = Vb + ((i + 1) & 1) * 4096;
#pragma unroll
            for (int j = 0; j < 2; ++j) {
                int rb = (2 * wv + j) * 8;
                glds16(Kp + (size_t)(t0 + rb + lrow) * PDIM + lcol, Kn + rb * 64);
                glds16(Vtp + (size_t)(rb + lrow) * SEQK + t0 + lcol, Vn + rb * 64);
            }
        }

        // K tile fragments once, reused for both y-groups
        short8 aK[2][4];
#pragma unroll
        for (int ks = 0; ks < 2; ++ks)
#pragma unroll
            for (int t = 0; t < 4; ++t)
                aK[ks][t] = *(const short8*)(Kc + (16 * t + c16) * 64 + ((4 * ks + g) ^ c8) * 8);

        // Phase 1: S^T = K_tile . Q^T per y; exp2 in-lane; P via LDS round
        // trip (wave-private, 2KB) into registers aP[y][ks]
        short8 aP[2][2];
#pragma unroll
        for (int y = 0; y < 2; ++y) {
            f32x4 s[4] = {z, z, z, z};
#pragma unroll
            for (int ks = 0; ks < 2; ++ks)
#pragma unroll
                for (int t = 0; t < 4; ++t)
                    s[t] = __builtin_amdgcn_mfma_f32_16x16x32_bf16(aK[ks][t], bQ[y][ks], s[t], 0, 0, 0);
#pragma unroll
            for (int t = 0; t < 4; ++t) {
                float p0 = exp2_raw(s[t][0]);
                float p1 = exp2_raw(s[t][1]);
                float p2 = exp2_raw(s[t][2]);
                float p3 = exp2_raw(s[t][3]);
                uint2 w2;
                w2.x = pack_bf16_rh(p0, p1);
                w2.y = pack_bf16_rh(p2, p3);
                int phys = (2 * t + (g >> 1)) ^ c8;
                *(uint2*)(PsW + c16 * 64 + phys * 8 + 4 * (g & 1)) = w2;
            }
#pragma unroll
            for (int ks = 0; ks < 2; ++ks)
                aP[y][ks] = *(const short8*)(PsW + c16 * 64 + ((4 * ks + g) ^ c8) * 8);
        }

        // Phase 2: O += P @ V ; l += P @ ones. bV read once, reused both y's.
#pragma unroll
        for (int ks = 0; ks < 2; ++ks) {
#pragma unroll
            for (int y = 0; y < 2; ++y)
                lacc[y] = __builtin_amdgcn_mfma_f32_16x16x32_bf16(aP[y][ks], vones, lacc[y], 0, 0, 0);
#pragma unroll
            for (int u = 0; u < 4; ++u) {
                short8 bV = *(const short8*)(Vc + (16 * u + c16) * 64 + ((4 * ks + g) ^ c8) * 8);
#pragma unroll
                for (int y = 0; y < 2; ++y)
                    oacc[y][u] = __builtin_amdgcn_mfma_f32_16x16x32_bf16(aP[y][ks], bV, oacc[y][u], 0, 0, 0);
            }
        }
    }

    // Epilogue: normalize in-register (lane holds lacc[y][r] = l of q-row
    // 32wv+16y+4g+r, replicated across c16), write single normalized rawO.
    // Block = one 128-tile: rawblk = (b*8+h)*16 + qt; m = 2*wv + y;
    // slot = m*4 + u; lane: rows r=0..3 (q = 16m+4g+r), col 16u+c16.
    const int rawblk = (b * NHEADS + h) * 16 + qt;
    unsigned int* rbase = rawO + (size_t)rawblk * 4096;
#pragma unroll
    for (int y = 0; y < 2; ++y) {
        float iv[4];
#pragma unroll
        for (int r = 0; r < 4; ++r)
            iv[r] = 1.0f / lacc[y][r];
#pragma unroll
        for (int u = 0; u < 4; ++u) {
            int slot = (2 * wv + y) * 4 + u;
            uint2 w2;
            w2.x = pack_bf16_rh(oacc[y][u][0] * iv[0], oacc[y][u][1] * iv[1]);
            w2.y = pack_bf16_rh(oacc[y][u][2] * iv[2], oacc[y][u][3] * iv[3]);
            *(uint2*)(rbase + slot * 128 + lane * 2) = w2;
        }
    }
}

// ---------------------------------------------------------------------------
// Output projection R17 (= verified R15 version): pure GEMM over
// pre-normalized bf16 O. rawO words are bit-sliced straight into XtS
// (no Lraw, no ivS, no float math before the MFMAs).
// 32-row tiles, grid 256; TWO chunks of FOUR heads each.
// ---------------------------------------------------------------------------
__global__ __launch_bounds__(256) void out_proj_kernel(
    const unsigned int* __restrict__ rawO,
    const unsigned short* __restrict__ Wt, const float* __restrict__ bo,
    float* __restrict__ out)
{
    __shared__ unsigned short XtS[32 * 264];   // 16896 B
    __shared__ unsigned short WtS[64 * 264];   // 33792 B

    const int tid = threadIdx.x;
    const int wv = tid >> 6, lane = tid & 63;
    const int g = lane >> 4, c16 = lane & 15;
    const int row0 = blockIdx.x * 32;
    const int b = row0 >> 11;
    const int qt = (row0 & 2047) >> 7;
    const int off = row0 & 127;                // 0/32/64/96 within attn 128-tile
    const unsigned short* W = Wt + (size_t)10 * 32768;

    const int sm = wv & 1;
    const int uh = wv >> 1;

    f32x4 z = {0.f, 0.f, 0.f, 0.f};
    f32x4 acc[2] = {z, z};

    for (int ch = 0; ch < 2; ++ch) {
        const int h0 = 4 * ch;
        // W loads: 64 n-rows x 256 k (4 heads, contiguous within each row)
        uint4 wreg[8];
        int wrow[8], wkk[8];
#pragma unroll
        for (int it = 0; it < 8; ++it) {
            int flat = tid * 8 + 2048 * it;
            wrow[it] = flat >> 8; wkk[it] = flat & 255;
            wreg[it] = *(const uint4*)(W + (size_t)wrow[it] * 512 + h0 * 64 + wkk[it]);
        }
        // O loads: per head hh, wave covers local slots 2wv, 2wv+1 (bf16,
        // already normalized by attn) — pure bit-slice, no arithmetic
        unsigned short vv[4][2][4];   // [hh][sl][r]
#pragma unroll
        for (int hh = 0; hh < 4; ++hh) {
            int h = h0 + hh;
            int rb0 = (b * NHEADS + h) * 16 + qt;
            const unsigned int* p0 = rawO + (size_t)rb0 * 4096;
#pragma unroll
            for (int sl = 0; sl < 2; ++sl) {
                int s_local = 2 * wv + sl;
                int m = s_local >> 2, u = s_local & 3;
                int sglob = ((off >> 4) + m) * 4 + u;
                uint2 a0 = *(const uint2*)(p0 + sglob * 128 + lane * 2);
                vv[hh][sl][0] = (unsigned short)(a0.x);
                vv[hh][sl][1] = (unsigned short)(a0.x >> 16);
                vv[hh][sl][2] = (unsigned short)(a0.y);
                vv[hh][sl][3] = (unsigned short)(a0.y >> 16);
            }
        }
        __syncthreads();   // prev chunk's MFMA reads done
#pragma unroll
        for (int it = 0; it < 8; ++it)
            *(uint4*)(&WtS[wrow[it] * 264 + wkk[it]]) = wreg[it];
#pragma unroll
        for (int hh = 0; hh < 4; ++hh)
#pragma unroll
            for (int sl = 0; sl < 2; ++sl) {
                int s_local = 2 * wv + sl;
                int m = s_local >> 2, u = s_local & 3;
#pragma unroll
                for (int r = 0; r < 4; ++r)
                    XtS[(16 * m + 4 * g + r) * 264 + hh * 64 + 16 * u + c16] = vv[hh][sl][r];
            }
        __syncthreads();

#pragma unroll
        for (int hh = 0; hh < 4; ++hh)
#pragma unroll
            for (int ks = 0; ks < 2; ++ks) {
                short8 aX = *(const short8*)(&XtS[(16 * sm + c16) * 264 + hh * 64 + 32 * ks + 8 * g]);
#pragma unroll
                for (int uu = 0; uu < 2; ++uu) {
                    int u = 2 * uh + uu;
                    short8 bW = *(const short8*)(&WtS[(16 * u + c16) * 264 + hh * 64 + 32 * ks + 8 * g]);
                    acc[uu] = __builtin_amdgcn_mfma_f32_16x16x32_bf16(aX, bW, acc[uu], 0, 0, 0);
                }
            }
    }

#pragma unroll
    for (int uu = 0; uu < 2; ++uu) {
        int u = 2 * uh + uu;
        float bb = bo[16 * u + c16];
#pragma unroll
        for (int r = 0; r < 4; ++r)
            out[(size_t)(row0 + 16 * sm + 4 * g + r) * 64 + 16 * u + c16] = acc[uu][r] + bb;
    }
}

// ---------------------------------------------------------------------------
extern "C" void kernel_launch(void* const* d_in, const int* in_sizes, int n_in,
                              void* d_out, int out_size, void* d_ws, size_t ws_size,
                              hipStream_t stream) {
    const float* query  = (const float*)d_in[0];
    const float* store_ = (const float*)d_in[1];
    const float* Wq     = (const float*)d_in[2];
    const float* bq     = (const float*)d_in[3];
    const float* Wk     = (const float*)d_in[4];
    const float* bk     = (const float*)d_in[5];
    const float* Wv     = (const float*)d_in[6];
    const float* bv     = (const float*)d_in[7];
    const float* Wo     = (const float*)d_in[8];
    const float* bo     = (const float*)d_in[9];
    float* out = (float*)d_out;

    // workspace: Wt 0.7MB | Qbuf 8MB | Kbuf 1MB | Vt 1MB | rawO 8.4MB
    unsigned short* Wt   = (unsigned short*)d_ws;
    unsigned short* Qbuf = Wt + (size_t)11 * 32768;
    unsigned short* Kbuf = Qbuf + (size_t)BATCH * NHEADS * SEQQ * PDIM;
    unsigned short* Vtbuf = Kbuf + (size_t)BATCH * SEQK * PDIM;
    unsigned int* rawO   = (unsigned int*)(Vtbuf + (size_t)BATCH * PDIM * SEQK);

    convert_w_kernel<<<88, 256, 0, stream>>>(Wq, Wk, Wv, Wo, Wt);

    dim3 gProj((BATCH * SEQQ) / 32, 3);
    qkv_proj_kernel<<<gProj, 256, 0, stream>>>(query, store_, Wt, bq, bk, bv,
                                               Qbuf, Kbuf, Vtbuf);

    dim3 gAttn(SEQQ / 128, NHEADS, BATCH);
    attn_kernel<<<gAttn, 256, 0, stream>>>(Qbuf, Kbuf, Vtbuf, rawO);

    out_proj_kernel<<<(BATCH * SEQQ) / 32, 256, 0, stream>>>(rawO, Wt, bo, out);
}

// Round 9
// 152.482 us; speedup vs baseline: 1.0257x; 1.0257x over previous
//
#include <hip/hip_runtime.h>
#include <math.h>

// Problem constants (MultiQueryAttention_20229295964202)
#define BATCH   4
#define SEQQ    2048
#define SEQK    2048
#define DMODEL  512
#define NHEADS  8
#define PDIM    64

#define QSCALE  0.18033688f   // 0.125 * log2(e); folded into Wq/bq; exp2 softmax

typedef __attribute__((ext_vector_type(8))) short short8;   // 8 bf16 (4 VGPRs)
typedef __attribute__((ext_vector_type(4))) float f32x4;    // MFMA C/D frag

__device__ __forceinline__ unsigned short f2bf(float x) {   // RNE
    unsigned u = __builtin_bit_cast(unsigned, x);
    u += 0x7fffu + ((u >> 16) & 1u);
    return (unsigned short)(u >> 16);
}
__device__ __forceinline__ unsigned pack_bf16_rh(float lo, float hi) {
    unsigned ul = __builtin_bit_cast(unsigned, lo) + 0x8000u;
    unsigned uh = __builtin_bit_cast(unsigned, hi) + 0x8000u;
    return __builtin_amdgcn_perm(uh, ul, 0x07060302u);  // [uh.hi16 : ul.hi16]
}
__device__ __forceinline__ float bf2f_lo(unsigned w) {
    return __builtin_bit_cast(float, w << 16);
}
__device__ __forceinline__ float bf2f_hi(unsigned w) {
    return __builtin_bit_cast(float, w & 0xFFFF0000u);
}
__device__ __forceinline__ float exp2_raw(float x) {        // raw v_exp_f32
    return __builtin_amdgcn_exp2f(x);
}
// async global->LDS, 16B/lane; lds base is wave-uniform, HW adds lane*16
__device__ __forceinline__ void glds16(const void* g, void* l) {
    __builtin_amdgcn_global_load_lds(
        (const __attribute__((address_space(1))) void*)g,
        (__attribute__((address_space(3))) void*)l, 16, 0, 0);
}

// ---------------------------------------------------------------------------
// Weight transpose: Wt[mat][n][k] bf16 (mat 0-7=Wq*QSCALE, 8=Wk, 9=Wv, 10=Wo).
// grid 88 = (mat, k-chunk): no serial loop.
// ---------------------------------------------------------------------------
__global__ __launch_bounds__(256) void convert_w_kernel(
    const float* __restrict__ Wq, const float* __restrict__ Wk,
    const float* __restrict__ Wv, const float* __restrict__ Wo,
    unsigned short* __restrict__ Wt)
{
    const int tid = threadIdx.x;
    const int mat = blockIdx.x >> 3;           // 0..10
    const int k0 = (blockIdx.x & 7) << 6;      // 0..448
    const float sc = (mat < 8) ? QSCALE : 1.0f;
    const float* src = (mat < 8) ? (Wq + (size_t)mat * 32768)
                     : (mat == 8) ? Wk : (mat == 9) ? Wv : Wo;
    __shared__ unsigned short T[64][72];       // [n][k-sub], padded
#pragma unroll
    for (int it = 0; it < 4; ++it) {
        int flat = tid * 4 + 1024 * it;        // k*64 + n
        int k = flat >> 6, n = flat & 63;
        float4 v = *(const float4*)(src + (size_t)(k0 + k) * 64 + n);
        T[n + 0][k] = f2bf(v.x * sc);
        T[n + 1][k] = f2bf(v.y * sc);
        T[n + 2][k] = f2bf(v.z * sc);
        T[n + 3][k] = f2bf(v.w * sc);
    }
    __syncthreads();
    int n = tid >> 2, kk = (tid & 3) * 16;
    uint4 w0 = *(const uint4*)(&T[n][kk]);
    uint4 w1 = *(const uint4*)(&T[n][kk + 8]);
    *(uint4*)(Wt + (size_t)mat * 32768 + (size_t)n * 512 + k0 + kk) = w0;
    *(uint4*)(Wt + (size_t)mat * 32768 + (size_t)n * 512 + k0 + kk + 8) = w1;
}

// ---------------------------------------------------------------------------
// QKV projection, fp32 X read directly (cvt in staging). 32-row x 256-col
// tiles; grid (256, 3): slot 0 = heads 0-3, slot 1 = heads 4-7, slot 2 = K|V.
// X float4 loads for the next chunk are issued AFTER the second barrier so
// their L3 latency hides under the MFMAs.
// ---------------------------------------------------------------------------
__global__ __launch_bounds__(256, 4) void qkv_proj_kernel(
    const float* __restrict__ query, const float* __restrict__ store_,
    const unsigned short* __restrict__ Wt,
    const float* __restrict__ bq, const float* __restrict__ bk,
    const float* __restrict__ bv,
    unsigned short* __restrict__ Qbuf, unsigned short* __restrict__ Kbuf,
    unsigned short* __restrict__ Vtbuf)
{
    __shared__ unsigned short Xt[2560];         // X tile [32][72] / Vlds [64][40]
    __shared__ unsigned short Wtile[256 * 64];  // 32768 B, XOR swizzle

    const int slot = blockIdx.y;
    const int row0 = blockIdx.x * 32;
    const int b = row0 >> 11;
    const int s0 = row0 & 2047;

    const float* X = ((slot < 2) ? query : store_) + (size_t)row0 * 512;
    const unsigned short* Wbase = Wt + (size_t)(slot * 4) * 32768;  // slot2 -> mats 8,9

    const int tid = threadIdx.x;
    const int wv = tid >> 6, lane = tid & 63;
    const int g = lane >> 4, c16 = lane & 15;
    const int c8 = c16 & 7;
    const int sm = wv & 1;
    const int uh = wv >> 1;
    const int lrow = lane >> 3;
    const int lcol = ((lane & 7) ^ lrow) * 8;   // swizzled col (shorts)

    f32x4 z = {0.f, 0.f, 0.f, 0.f};
    f32x4 acc[8] = {z, z, z, z, z, z, z, z};

    const int xrow = tid >> 3;                  // 0..31
    const int xcol = (tid & 7) * 8;             // 0..56
    const int nwr = (slot < 2) ? 8 : 4;         // W row-blocks per wave

    float4 xa = *(const float4*)(X + (size_t)xrow * 512 + xcol);
    float4 xb = *(const float4*)(X + (size_t)xrow * 512 + xcol + 4);

    for (int k0 = 0; k0 < 512; k0 += 64) {
        __syncthreads();   // prev chunk's MFMA reads of Xt/Wtile done
        for (int j = 0; j < nwr; ++j) {
            int rb = (nwr * wv + j) * 8;
            glds16(Wbase + (size_t)(rb + lrow) * 512 + k0 + lcol, Wtile + rb * 64);
        }
        ushort4 o0, o1;
        o0.x = f2bf(xa.x); o0.y = f2bf(xa.y); o0.z = f2bf(xa.z); o0.w = f2bf(xa.w);
        o1.x = f2bf(xb.x); o1.y = f2bf(xb.y); o1.z = f2bf(xb.z); o1.w = f2bf(xb.w);
        *(ushort4*)(&Xt[xrow * 72 + xcol]) = o0;
        *(ushort4*)(&Xt[xrow * 72 + xcol + 4]) = o1;
        __syncthreads();   // drains glds + lds stores

        if (k0 < 448) {    // prefetch next X chunk; lands under the MFMAs
            xa = *(const float4*)(X + (size_t)xrow * 512 + k0 + 64 + xcol);
            xb = *(const float4*)(X + (size_t)xrow * 512 + k0 + 64 + xcol + 4);
        }

        if (slot < 2) {
#pragma unroll
            for (int ks = 0; ks < 2; ++ks) {
                short8 aX = *(const short8*)(&Xt[(16 * sm + c16) * 72 + 32 * ks + 8 * g]);
#pragma unroll
                for (int uu = 0; uu < 8; ++uu) {
                    int u = 8 * uh + uu;
                    short8 bW = *(const short8*)(Wtile + (16 * u + c16) * 64 + ((4 * ks + g) ^ c8) * 8);
                    acc[uu] = __builtin_amdgcn_mfma_f32_16x16x32_bf16(aX, bW, acc[uu], 0, 0, 0);
                }
            }
        } else {
#pragma unroll
            for (int ks = 0; ks < 2; ++ks) {
                short8 aX = *(const short8*)(&Xt[(16 * sm + c16) * 72 + 32 * ks + 8 * g]);
#pragma unroll
                for (int uu = 0; uu < 4; ++uu) {
                    int u = 4 * uh + uu;
                    short8 bW = *(const short8*)(Wtile + (16 * u + c16) * 64 + ((4 * ks + g) ^ c8) * 8);
                    acc[uu] = __builtin_amdgcn_mfma_f32_16x16x32_bf16(aX, bW, acc[uu], 0, 0, 0);
                }
            }
        }
    }

    if (slot < 2) {
        // 4 Q heads; wave uh covers heads 2uh, 2uh+1 of this slot
#pragma unroll
        for (int uu = 0; uu < 8; ++uu) {
            int u = 8 * uh + uu;
            int head = 4 * slot + (u >> 2);
            int pc = 16 * (u & 3) + c16;
            float bb = QSCALE * bq[head * 64 + pc];
            unsigned short* Y = Qbuf + ((size_t)(b * NHEADS + head) * SEQQ + s0) * PDIM;
#pragma unroll
            for (int r = 0; r < 4; ++r)
                Y[(size_t)(16 * sm + 4 * g + r) * PDIM + pc] = f2bf(acc[uu][r] + bb);
        }
    } else {
        // uh==0 waves hold K (u 0..3); uh==1 waves hold V (u 4..7)
        if (uh == 0) {
            unsigned short* Yk = Kbuf + (size_t)row0 * PDIM;
#pragma unroll
            for (int uu = 0; uu < 4; ++uu) {
                float bb = bk[16 * uu + c16];
#pragma unroll
                for (int r = 0; r < 4; ++r)
                    Yk[(size_t)(16 * sm + 4 * g + r) * PDIM + 16 * uu + c16] =
                        f2bf(acc[uu][r] + bb);
            }
        }
        __syncthreads();   // Xt MFMA reads done; reuse as Vlds[64][40]
        if (uh == 1) {
#pragma unroll
            for (int uu = 0; uu < 4; ++uu) {
                int p = 16 * uu + c16;
                float bb = bv[p];
#pragma unroll
                for (int r = 0; r < 4; ++r)
                    Xt[p * 40 + 16 * sm + 4 * g + r] = f2bf(acc[uu][r] + bb);
            }
        }
        __syncthreads();
        int p = tid >> 2, soff = (tid & 3) * 8;
        uint4 w = *(const uint4*)(&Xt[p * 40 + soff]);
        *(uint4*)(Vtbuf + (size_t)b * PDIM * SEQK + (size_t)p * SEQK + s0 + soff) = w;
    }
}

// ---------------------------------------------------------------------------
// Flash attention R18: exact R14 structure (best measured 45.7us: 256
// q/block, 64 q/wave y=0..3, K-SPLIT x2, glds dbuf, one barrier/iter,
// 2 blocks/CU) + s_setprio(1) around the MFMA clusters (T5; m191 measured
// +4-7% on attn). With 2 independent blocks/CU the CU scheduler has waves
// at different phases; raising MFMA-cluster priority keeps the matrix pipe
// fed while other waves run exp2/pack VALU.
// ---------------------------------------------------------------------------
__global__ __launch_bounds__(256, 2) void attn_kernel(
    const unsigned short* __restrict__ Qbuf,
    const unsigned short* __restrict__ Kbuf,
    const unsigned short* __restrict__ Vtbuf,
    unsigned int* __restrict__ rawO,    // [rawblk][slot 32][lane 64] uint2
    float* __restrict__ Lraw)           // [rawblk][128]
{
    __shared__ unsigned short smem[20480];  // K dbuf 8192 | V dbuf 8192 | Ps 4096
    unsigned short* Kb = smem;
    unsigned short* Vb = smem + 8192;
    unsigned short* Ps = smem + 16384;

    const int tid = threadIdx.x;
    const int wv = tid >> 6;
    const int lane = tid & 63;
    const int g = lane >> 4;
    const int c16 = lane & 15;
    const int c8 = c16 & 7;
    const int split = blockIdx.z & 1;
    const int b = blockIdx.z >> 1;
    const int h = blockIdx.y;
    const int qt = blockIdx.x;
    const int q0 = qt * 256;

    const int lrow = lane >> 3;
    const int lcol = ((lane & 7) ^ lrow) * 8;

    // stage 256 q rows (32 KB) into the K/V dbuf region
    const unsigned short* Qp = Qbuf + ((size_t)(b * NHEADS + h) * SEQQ + q0) * PDIM;
#pragma unroll
    for (int j = 0; j < 8; ++j) {
        int rowblk = (8 * wv + j) * 8;
        glds16(Qp + (size_t)(rowblk + lrow) * PDIM + lcol, smem + rowblk * 64);
    }
    __syncthreads();

    short8 bQ[4][2];   // B[k=p][n=query=c16], wave rows 64*wv + 16*y
#pragma unroll
    for (int y = 0; y < 4; ++y)
#pragma unroll
        for (int ks = 0; ks < 2; ++ks)
            bQ[y][ks] = *(const short8*)(smem + (64 * wv + 16 * y + c16) * 64 +
                                         ((4 * ks + g) ^ c8) * 8);
    __syncthreads();

    const unsigned short* Kp  = Kbuf  + (size_t)b * SEQK * PDIM + (size_t)split * 1024 * PDIM;
    const unsigned short* Vtp = Vtbuf + (size_t)b * PDIM * SEQK + split * 1024;

#pragma unroll
    for (int j = 0; j < 2; ++j) {
        int rb = (2 * wv + j) * 8;
        glds16(Kp + (size_t)(rb + lrow) * PDIM + lcol, Kb + rb * 64);
        glds16(Vtp + (size_t)(rb + lrow) * SEQK + lcol, Vb + rb * 64);
    }

    const short one_bf = (short)0x3F80;   // bf16 1.0
    short8 vones = {one_bf, one_bf, one_bf, one_bf, one_bf, one_bf, one_bf, one_bf};

    f32x4 z = {0.f, 0.f, 0.f, 0.f};
    f32x4 oacc[4][4] = {{z, z, z, z}, {z, z, z, z}, {z, z, z, z}, {z, z, z, z}};
    f32x4 lacc[4] = {z, z, z, z};
    unsigned short* PsW = Ps + wv * 1024;   // 16 x 64, reused per y (in-order LDS)

    for (int i = 0; i < 16; ++i) {
        __syncthreads();   // drains glds(tile i); prev compute reads done
        const unsigned short* Kc = Kb + (i & 1) * 4096;
        const unsigned short* Vc = Vb + (i & 1) * 4096;
        if (i < 15) {
            int t0 = (i + 1) * 64;
            unsigned short* Kn = Kb + ((i + 1) & 1) * 4096;
            unsigned short* Vn = Vb + ((i + 1) & 1) * 4096;
#pragma unroll
            for (int j = 0; j < 2; ++j) {
                int rb = (2 * wv + j) * 8;
                glds16(Kp + (size_t)(t0 + rb + lrow) * PDIM + lcol, Kn + rb * 64);
                glds16(Vtp + (size_t)(rb + lrow) * SEQK + t0 + lcol, Vn + rb * 64);
            }
        }

        // K tile fragments once, reused for all 4 y-groups
        short8 aK[2][4];
#pragma unroll
        for (int ks = 0; ks < 2; ++ks)
#pragma unroll
            for (int t = 0; t < 4; ++t)
                aK[ks][t] = *(const short8*)(Kc + (16 * t + c16) * 64 + ((4 * ks + g) ^ c8) * 8);

        // Phase 1: S^T = K_tile . Q^T per y; exp2 in-lane; P via LDS round
        // trip (wave-private, 2KB) into registers aP[y][ks]
        short8 aP[4][2];
#pragma unroll
        for (int y = 0; y < 4; ++y) {
            f32x4 s[4] = {z, z, z, z};
            __builtin_amdgcn_s_setprio(1);
#pragma unroll
            for (int ks = 0; ks < 2; ++ks)
#pragma unroll
                for (int t = 0; t < 4; ++t)
                    s[t] = __builtin_amdgcn_mfma_f32_16x16x32_bf16(aK[ks][t], bQ[y][ks], s[t], 0, 0, 0);
            __builtin_amdgcn_s_setprio(0);
#pragma unroll
            for (int t = 0; t < 4; ++t) {
                float p0 = exp2_raw(s[t][0]);
                float p1 = exp2_raw(s[t][1]);
                float p2 = exp2_raw(s[t][2]);
                float p3 = exp2_raw(s[t][3]);
                uint2 w2;
                w2.x = pack_bf16_rh(p0, p1);
                w2.y = pack_bf16_rh(p2, p3);
                int phys = (2 * t + (g >> 1)) ^ c8;
                *(uint2*)(PsW + c16 * 64 + phys * 8 + 4 * (g & 1)) = w2;
            }
#pragma unroll
            for (int ks = 0; ks < 2; ++ks)
                aP[y][ks] = *(const short8*)(PsW + c16 * 64 + ((4 * ks + g) ^ c8) * 8);
        }

        // Phase 2: O += P @ V ; l += P @ ones. bV read once, reused 4 y's.
        __builtin_amdgcn_s_setprio(1);
#pragma unroll
        for (int ks = 0; ks < 2; ++ks) {
#pragma unroll
            for (int y = 0; y < 4; ++y)
                lacc[y] = __builtin_amdgcn_mfma_f32_16x16x32_bf16(aP[y][ks], vones, lacc[y], 0, 0, 0);
#pragma unroll
            for (int u = 0; u < 4; ++u) {
                short8 bV = *(const short8*)(Vc + (16 * u + c16) * 64 + ((4 * ks + g) ^ c8) * 8);
#pragma unroll
                for (int y = 0; y < 4; ++y)
                    oacc[y][u] = __builtin_amdgcn_mfma_f32_16x16x32_bf16(aP[y][ks], bV, oacc[y][u], 0, 0, 0);
            }
        }
        __builtin_amdgcn_s_setprio(0);
    }

    // Epilogue: rawO/Lraw layout: 128-tile qtg = qt*2 + (wv>>1);
    // row-group m = 4*(wv&1) + y.
    const int qtg = qt * 2 + (wv >> 1);
    const int rawblk = ((b * NHEADS + h) * 16 + qtg) * 2 + split;
    unsigned int* rbase = rawO + (size_t)rawblk * 4096;
#pragma unroll
    for (int y = 0; y < 4; ++y) {
#pragma unroll
        for (int u = 0; u < 4; ++u) {
            int slot = (4 * (wv & 1) + y) * 4 + u;
            uint2 w2;
            w2.x = pack_bf16_rh(oacc[y][u][0], oacc[y][u][1]);
            w2.y = pack_bf16_rh(oacc[y][u][2], oacc[y][u][3]);
            *(uint2*)(rbase + slot * 128 + lane * 2) = w2;
        }
        if (c16 == 0) {
#pragma unroll
            for (int r = 0; r < 4; ++r)
                Lraw[(size_t)rawblk * 128 + 64 * (wv & 1) + 16 * y + 4 * g + r] = lacc[y][r];
        }
    }
}

// ---------------------------------------------------------------------------
// Output projection fused with split-combine: out = concat(O/l) @ Wo + bo.
// iv = 1/(l0+l1) staged ONCE into LDS. 32-row tiles, grid 256; TWO chunks
// of FOUR heads each.
// ---------------------------------------------------------------------------
__global__ __launch_bounds__(256) void out_proj_kernel(
    const unsigned int* __restrict__ rawO, const float* __restrict__ Lraw,
    const unsigned short* __restrict__ Wt, const float* __restrict__ bo,
    float* __restrict__ out)
{
    __shared__ unsigned short XtS[32 * 264];   // 16896 B
    __shared__ unsigned short WtS[64 * 264];   // 33792 B
    __shared__ float ivS[8][32];               // 1024 B

    const int tid = threadIdx.x;
    const int wv = tid >> 6, lane = tid & 63;
    const int g = lane >> 4, c16 = lane & 15;
    const int row0 = blockIdx.x * 32;
    const int b = row0 >> 11;
    const int qt = (row0 & 2047) >> 7;
    const int off = row0 & 127;                // 0/32/64/96 within attn 128-tile
    const unsigned short* W = Wt + (size_t)10 * 32768;

    const int sm = wv & 1;
    const int uh = wv >> 1;

    // iv staging: thread (h = tid>>5, row = tid&31)
    {
        int hh = tid >> 5, row = tid & 31;
        int rb0 = ((b * NHEADS + hh) * 16 + qt) * 2;
        float l01 = Lraw[(size_t)rb0 * 128 + off + row] +
                    Lraw[(size_t)(rb0 + 1) * 128 + off + row];
        ivS[hh][row] = 1.0f / l01;
    }
    __syncthreads();

    f32x4 z = {0.f, 0.f, 0.f, 0.f};
    f32x4 acc[2] = {z, z};

    for (int ch = 0; ch < 2; ++ch) {
        const int h0 = 4 * ch;
        // W loads: 64 n-rows x 256 k (4 heads, contiguous within each row)
        uint4 wreg[8];
        int wrow[8], wkk[8];
#pragma unroll
        for (int it = 0; it < 8; ++it) {
            int flat = tid * 8 + 2048 * it;
            wrow[it] = flat >> 8; wkk[it] = flat & 255;
            wreg[it] = *(const uint4*)(W + (size_t)wrow[it] * 512 + h0 * 64 + wkk[it]);
        }
        // rawO combine: per head hh, wave stages local slots 2wv, 2wv+1
        unsigned short vv[4][2][4];   // [hh][sl][r]
#pragma unroll
        for (int hh = 0; hh < 4; ++hh) {
            int h = h0 + hh;
            int rb0 = ((b * NHEADS + h) * 16 + qt) * 2;
            const unsigned int* p0 = rawO + (size_t)rb0 * 4096;
            const unsigned int* p1 = rawO + (size_t)(rb0 + 1) * 4096;
#pragma unroll
            for (int sl = 0; sl < 2; ++sl) {
                int s_local = 2 * wv + sl;
                int m = s_local >> 2, u = s_local & 3;
                int sglob = ((off >> 4) + m) * 4 + u;
                uint2 a0 = *(const uint2*)(p0 + sglob * 128 + lane * 2);
                uint2 a1 = *(const uint2*)(p1 + sglob * 128 + lane * 2);
                float iv[4];
#pragma unroll
                for (int r = 0; r < 4; ++r)
                    iv[r] = ivS[h][16 * m + 4 * g + r];
                vv[hh][sl][0] = f2bf((bf2f_lo(a0.x) + bf2f_lo(a1.x)) * iv[0]);
                vv[hh][sl][1] = f2bf((bf2f_hi(a0.x) + bf2f_hi(a1.x)) * iv[1]);
                vv[hh][sl][2] = f2bf((bf2f_lo(a0.y) + bf2f_lo(a1.y)) * iv[2]);
                vv[hh][sl][3] = f2bf((bf2f_hi(a0.y) + bf2f_hi(a1.y)) * iv[3]);
            }
        }
        __syncthreads();   // prev chunk's MFMA reads done
#pragma unroll
        for (int it = 0; it < 8; ++it)
            *(uint4*)(&WtS[wrow[it] * 264 + wkk[it]]) = wreg[it];
#pragma unroll
        for (int hh = 0; hh < 4; ++hh)
#pragma unroll
            for (int sl = 0; sl < 2; ++sl) {
                int s_local = 2 * wv + sl;
                int m = s_local >> 2, u = s_local & 3;
#pragma unroll
                for (int r = 0; r < 4; ++r)
                    XtS[(16 * m + 4 * g + r) * 264 + hh * 64 + 16 * u + c16] = vv[hh][sl][r];
            }
        __syncthreads();

#pragma unroll
        for (int hh = 0; hh < 4; ++hh)
#pragma unroll
            for (int ks = 0; ks < 2; ++ks) {
                short8 aX = *(const short8*)(&XtS[(16 * sm + c16) * 264 + hh * 64 + 32 * ks + 8 * g]);
#pragma unroll
                for (int uu = 0; uu < 2; ++uu) {
                    int u = 2 * uh + uu;
                    short8 bW = *(const short8*)(&WtS[(16 * u + c16) * 264 + hh * 64 + 32 * ks + 8 * g]);
                    acc[uu] = __builtin_amdgcn_mfma_f32_16x16x32_bf16(aX, bW, acc[uu], 0, 0, 0);
                }
            }
    }

#pragma unroll
    for (int uu = 0; uu < 2; ++uu) {
        int u = 2 * uh + uu;
        float bb = bo[16 * u + c16];
#pragma unroll
        for (int r = 0; r < 4; ++r)
            out[(size_t)(row0 + 16 * sm + 4 * g + r) * 64 + 16 * u + c16] = acc[uu][r] + bb;
    }
}

// ---------------------------------------------------------------------------
extern "C" void kernel_launch(void* const* d_in, const int* in_sizes, int n_in,
                              void* d_out, int out_size, void* d_ws, size_t ws_size,
                              hipStream_t stream) {
    const float* query  = (const float*)d_in[0];
    const float* store_ = (const float*)d_in[1];
    const float* Wq     = (const float*)d_in[2];
    const float* bq     = (const float*)d_in[3];
    const float* Wk     = (const float*)d_in[4];
    const float* bk     = (const float*)d_in[5];
    const float* Wv     = (const float*)d_in[6];
    const float* bv     = (const float*)d_in[7];
    const float* Wo     = (const float*)d_in[8];
    const float* bo     = (const float*)d_in[9];
    float* out = (float*)d_out;

    // workspace: Wt 0.7MB | Qbuf 8MB | Kbuf 1MB | Vt 1MB | rawO 16MB | Lraw 0.5MB
    unsigned short* Wt   = (unsigned short*)d_ws;
    unsigned short* Qbuf = Wt + (size_t)11 * 32768;
    unsigned short* Kbuf = Qbuf + (size_t)BATCH * NHEADS * SEQQ * PDIM;
    unsigned short* Vtbuf = Kbuf + (size_t)BATCH * SEQK * PDIM;
    unsigned int* rawO   = (unsigned int*)(Vtbuf + (size_t)BATCH * PDIM * SEQK);
    float* Lraw          = (float*)(rawO + (size_t)1024 * 4096);

    convert_w_kernel<<<88, 256, 0, stream>>>(Wq, Wk, Wv, Wo, Wt);

    dim3 gProj((BATCH * SEQQ) / 32, 3);
    qkv_proj_kernel<<<gProj, 256, 0, stream>>>(query, store_, Wt, bq, bk, bv,
                                               Qbuf, Kbuf, Vtbuf);

    dim3 gAttn(SEQQ / 256, NHEADS, BATCH * 2);
    attn_kernel<<<gAttn, 256, 0, stream>>>(Qbuf, Kbuf, Vtbuf, rawO, Lraw);

    out_proj_kernel<<<(BATCH * SEQQ) / 32, 256, 0, stream>>>(rawO, Lraw, Wt, bo, out);
}